// Round 2
// baseline (656.437 us; speedup 1.0000x reference)
//
#include <hip/hip_runtime.h>

#define LNUM 8
#define WD 128
#define BATCH 262144
#define TILES 4
#define BM 1024   // samples per block

typedef unsigned int u32;
typedef __attribute__((ext_vector_type(8))) short bf16x8;
typedef __attribute__((ext_vector_type(4))) float f32x4;

__device__ __forceinline__ u32 pk2(float x, float y){
  u32 a = __float_as_uint(x), b = __float_as_uint(y);
  a = (a + 0x7FFFu + ((a >> 16) & 1u)) >> 16;   // RNE f32->bf16
  b = (b + 0x7FFFu + ((b >> 16) & 1u)) >> 16;
  return a | (b << 16);
}
__device__ __forceinline__ float bflo(u32 v){ return __uint_as_float(v << 16); }
__device__ __forceinline__ float bfhi(u32 v){ return __uint_as_float(v & 0xFFFF0000u); }

// Stage a 128x128 fp32 weight matrix into LDS as bf16, row-major, XOR-swizzled.
// dst: 8192 dwords (row stride 64 dwords). Thread t: row j=t>>1, half h=t&1
// (64 floats -> 32 dwords at logical dword base h*32).
__device__ __forceinline__ void stage_W(const float* __restrict__ src, u32* dst, int tid){
  const int j = tid >> 1, h = tid & 1;
  const float* s = src + j * WD + h * 64;
  u32* drow = dst + j * 64;
  const int base = h * 32;                 // FIX: was h*16 (overlapped halves,
                                           // left dwords 48..63 uninitialized -> NaN)
  const u32 sz = (u32)((j & 7) << 2);
#pragma unroll
  for(int c = 0; c < 8; ++c){
    float4 f0 = *(const float4*)(s + c * 8);
    float4 f1 = *(const float4*)(s + c * 8 + 4);
    uint4 w;
    w.x = pk2(f0.x, f0.y); w.y = pk2(f0.z, f0.w);
    w.z = pk2(f1.x, f1.y); w.w = pk2(f1.z, f1.w);
    *(uint4*)(drow + (((u32)(base + c * 4)) ^ sz)) = w;
  }
}

// Stage 1: h1[j] = relu(u*W1[j] + b1[j]) -> H row (bf16), lane = sample.
__device__ __forceinline__ void mlp_in(float u, const float* __restrict__ W1,
                                       const float* __restrict__ b1, u32* Hb, int row){
  u32* hrow = Hb + row * 64;
  const u32 sz = (u32)((row & 7) << 2);
#pragma unroll
  for(int c = 0; c < 16; ++c){
    float4 w0 = *(const float4*)(W1 + c * 8);
    float4 w1 = *(const float4*)(W1 + c * 8 + 4);
    float4 g0 = *(const float4*)(b1 + c * 8);
    float4 g1 = *(const float4*)(b1 + c * 8 + 4);
    float h0 = fmaxf(fmaf(u, w0.x, g0.x), 0.f);
    float h1 = fmaxf(fmaf(u, w0.y, g0.y), 0.f);
    float h2 = fmaxf(fmaf(u, w0.z, g0.z), 0.f);
    float h3 = fmaxf(fmaf(u, w0.w, g0.w), 0.f);
    float h4 = fmaxf(fmaf(u, w1.x, g1.x), 0.f);
    float h5 = fmaxf(fmaf(u, w1.y, g1.y), 0.f);
    float h6 = fmaxf(fmaf(u, w1.z, g1.z), 0.f);
    float h7 = fmaxf(fmaf(u, w1.w, g1.w), 0.f);
    uint4 o;
    o.x = pk2(h0, h1); o.y = pk2(h2, h3); o.z = pk2(h4, h5); o.w = pk2(h6, h7);
    *(uint4*)(hrow + (((u32)(c * 4)) ^ sz)) = o;
  }
}

// Middle stage: H <- relu(W * H^T + b) via swapped-operand MFMA (16x16x32 bf16).
// Wave owns sample rows [wv*64, wv*64+64). A = W tile (M=j), B = H (N=sample).
__device__ __forceinline__ void mlp_mid(const u32* Wb, u32* Hb,
                                        const float* __restrict__ bias, int wv, int lane){
  const int lm = lane & 15, lg = lane >> 4;
  const f32x4 zero = {0.f, 0.f, 0.f, 0.f};
  f32x4 acc[8][4];
#pragma unroll
  for(int jt = 0; jt < 8; ++jt)
#pragma unroll
    for(int st = 0; st < 4; ++st) acc[jt][st] = zero;

#pragma unroll
  for(int kt = 0; kt < 4; ++kt){
    const u32 kdw = (u32)(kt * 16 + lg * 4);
    bf16x8 av[8], bv[4];
#pragma unroll
    for(int jt = 0; jt < 8; ++jt){
      int j = lm + 16 * jt;
      const u32* p = Wb + j * 64 + (kdw ^ (u32)((j & 7) << 2));
      av[jt] = __builtin_bit_cast(bf16x8, *(const uint4*)p);
    }
#pragma unroll
    for(int st = 0; st < 4; ++st){
      int s = wv * 64 + st * 16 + lm;
      const u32* p = Hb + s * 64 + (kdw ^ (u32)((s & 7) << 2));
      bv[st] = __builtin_bit_cast(bf16x8, *(const uint4*)p);
    }
#pragma unroll
    for(int jt = 0; jt < 8; ++jt)
#pragma unroll
      for(int st = 0; st < 4; ++st)
        acc[jt][st] = __builtin_amdgcn_mfma_f32_16x16x32_bf16(av[jt], bv[st], acc[jt][st], 0, 0, 0);
  }

  // epilogue: bias + relu, write back bf16.
  // m89 C/D map: N(sample) = lane&15, M(j) = (lane>>4)*4 + reg.
#pragma unroll
  for(int jt = 0; jt < 8; ++jt){
    const int j0 = jt * 16 + lg * 4;
    const float4 bs = *(const float4*)(bias + j0);
#pragma unroll
    for(int st = 0; st < 4; ++st){
      int s = wv * 64 + st * 16 + lm;
      float v0 = fmaxf(acc[jt][st][0] + bs.x, 0.f);
      float v1 = fmaxf(acc[jt][st][1] + bs.y, 0.f);
      float v2 = fmaxf(acc[jt][st][2] + bs.z, 0.f);
      float v3 = fmaxf(acc[jt][st][3] + bs.w, 0.f);
      u32* p = Hb + s * 64 + (((u32)(j0 >> 1)) ^ (u32)((s & 7) << 2));
      uint2 w; w.x = pk2(v0, v1); w.y = pk2(v2, v3);
      *(uint2*)p = w;
    }
  }
}

// Stage 4: dot(H row, W4) in fp32, lane = sample.
__device__ __forceinline__ float mlp_out(const float* __restrict__ W4, const u32* Hb, int row){
  const u32* hrow = Hb + row * 64;
  const u32 sz = (u32)((row & 7) << 2);
  float acc = 0.f;
#pragma unroll
  for(int c = 0; c < 16; ++c){
    uint4 h = *(const uint4*)(hrow + (((u32)(c * 4)) ^ sz));
    float4 w0 = *(const float4*)(W4 + c * 8);
    float4 w1 = *(const float4*)(W4 + c * 8 + 4);
    acc = fmaf(bflo(h.x), w0.x, acc); acc = fmaf(bfhi(h.x), w0.y, acc);
    acc = fmaf(bflo(h.y), w0.z, acc); acc = fmaf(bfhi(h.y), w0.w, acc);
    acc = fmaf(bflo(h.z), w1.x, acc); acc = fmaf(bfhi(h.z), w1.y, acc);
    acc = fmaf(bflo(h.w), w1.z, acc); acc = fmaf(bfhi(h.w), w1.w, acc);
  }
  return acc;
}

__device__ __forceinline__ void fence_lds(){ __builtin_amdgcn_sched_barrier(0); }

extern "C" __global__ void __launch_bounds__(256, 1)
flow_kernel(const float* __restrict__ x, const float* __restrict__ s_scale,
            const float* __restrict__ sW1, const float* __restrict__ sb1,
            const float* __restrict__ sW2, const float* __restrict__ sb2,
            const float* __restrict__ sW3, const float* __restrict__ sb3,
            const float* __restrict__ sW4, const float* __restrict__ sb4,
            const float* __restrict__ tW1, const float* __restrict__ tb1,
            const float* __restrict__ tW2, const float* __restrict__ tb2,
            const float* __restrict__ tW3, const float* __restrict__ tb3,
            const float* __restrict__ tW4, const float* __restrict__ tb4,
            float* __restrict__ out)
{
  __shared__ u32 Wlds[2][8192];     // 64 KB: W2 / W3 bf16, swizzled
  __shared__ u32 Hlds[16384];       // 64 KB: 256 rows x 128 bf16, swizzled

  const int tid = threadIdx.x;
  const int wv = tid >> 6, lane = tid & 63;
  const int blockBase = (int)blockIdx.x * BM;

  float2 abr[TILES];
  float  svr[TILES];
  const float2* x2 = (const float2*)x;
#pragma unroll
  for(int t = 0; t < TILES; ++t) abr[t] = x2[blockBase + t * 256 + tid];

  float* scat = out + 2 * BATCH;

#pragma unroll 1
  for(int i = 0; i < LNUM; ++i){
    const float sc = s_scale[i];
    const int parity = i & 1;

    // ---------- phase A: s-MLP ----------
    __syncthreads();                       // previous phase done reading Wlds
    stage_W(sW2 + i * (WD * WD), Wlds[0], tid);
    stage_W(sW3 + i * (WD * WD), Wlds[1], tid);
    __syncthreads();
#pragma unroll 1
    for(int t = 0; t < TILES; ++t){
      const int li = t * 256 + tid;
      float u = parity ? abr[t].y : abr[t].x;
      mlp_in(u, sW1 + i * WD, sb1 + i * WD, Hlds, tid);
      fence_lds();
      mlp_mid(Wlds[0], Hlds, sb2 + i * WD, wv, lane);
      fence_lds();
      mlp_mid(Wlds[1], Hlds, sb3 + i * WD, wv, lane);
      fence_lds();
      float pre = mlp_out(sW4 + i * WD, Hlds, tid) + sb4[i];
      float sv = sc * tanhf(pre);
      svr[t] = sv;
      scat[i * BATCH + blockBase + li] = sv;
    }

    // ---------- phase B: t-MLP + coupling update ----------
    __syncthreads();
    stage_W(tW2 + i * (WD * WD), Wlds[0], tid);
    stage_W(tW3 + i * (WD * WD), Wlds[1], tid);
    __syncthreads();
#pragma unroll 1
    for(int t = 0; t < TILES; ++t){
      float u = parity ? abr[t].y : abr[t].x;
      mlp_in(u, tW1 + i * WD, tb1 + i * WD, Hlds, tid);
      fence_lds();
      mlp_mid(Wlds[0], Hlds, tb2 + i * WD, wv, lane);
      fence_lds();
      mlp_mid(Wlds[1], Hlds, tb3 + i * WD, wv, lane);
      fence_lds();
      float pre = mlp_out(tW4 + i * WD, Hlds, tid) + tb4[i];
      float tv = tanhf(pre);
      float e = expf(svr[t]);
      if(parity) abr[t].x = e * abr[t].x + tv; else abr[t].y = e * abr[t].y + tv;
    }
  }

  float2* out2 = (float2*)out;
#pragma unroll
  for(int t = 0; t < TILES; ++t) out2[blockBase + t * 256 + tid] = abr[t];
}

extern "C" void kernel_launch(void* const* d_in, const int* in_sizes, int n_in,
                              void* d_out, int out_size, void* d_ws, size_t ws_size,
                              hipStream_t stream) {
  (void)in_sizes; (void)n_in; (void)d_ws; (void)ws_size; (void)out_size;
  const float* p[18];
  for(int k = 0; k < 18; ++k) p[k] = (const float*)d_in[k];
  dim3 grid(BATCH / BM), block(256);
  hipLaunchKernelGGL(flow_kernel, grid, block, 0, stream,
                     p[0], p[1], p[2], p[3], p[4], p[5], p[6], p[7], p[8], p[9],
                     p[10], p[11], p[12], p[13], p[14], p[15], p[16], p[17],
                     (float*)d_out);
}

// Round 3
// 532.549 us; speedup vs baseline: 1.2326x; 1.2326x over previous
//
#include <hip/hip_runtime.h>

#define LNUM 8
#define WD 128
#define BATCH 262144

typedef unsigned int u32;
typedef __attribute__((ext_vector_type(8))) short bf16x8;
typedef __attribute__((ext_vector_type(4))) float f32x4;

__device__ __forceinline__ u32 pk2(float x, float y){
  u32 a = __float_as_uint(x), b = __float_as_uint(y);
  a = (a + 0x7FFFu + ((a >> 16) & 1u)) >> 16;   // RNE f32->bf16
  b = (b + 0x7FFFu + ((b >> 16) & 1u)) >> 16;
  return a | (b << 16);
}

// Stage a 128x128 fp32 weight matrix into LDS as bf16, row-major, XOR-swizzled.
// dst: 8192 dwords (row stride 64). Thread t: row j=t>>1, half h=t&1.
__device__ __forceinline__ void stage_W(const float* __restrict__ src, u32* dst, int tid){
  const int j = tid >> 1, h = tid & 1;
  const float* s = src + j * WD + h * 64;
  u32* drow = dst + j * 64;
  const int base = h * 32;
  const u32 sz = (u32)((j & 7) << 2);
#pragma unroll
  for(int c = 0; c < 8; ++c){
    float4 f0 = *(const float4*)(s + c * 8);
    float4 f1 = *(const float4*)(s + c * 8 + 4);
    uint4 w;
    w.x = pk2(f0.x, f0.y); w.y = pk2(f0.z, f0.w);
    w.z = pk2(f1.x, f1.y); w.w = pk2(f1.z, f1.w);
    *(uint4*)(drow + (((u32)(base + c * 4)) ^ sz)) = w;
  }
}

// Full 4-stage MLP for one wave's 64 samples, H entirely in registers.
// Returns pre-activation scalar (before +b4, tanh) for this thread's own sample.
__device__ __forceinline__ float mlp_frag(
    float u, const u32* __restrict__ W2lds, const u32* __restrict__ W3lds,
    const float* __restrict__ W1, const float* __restrict__ b1,
    const float* __restrict__ b2, const float* __restrict__ b3,
    const float* __restrict__ W4, int lm, int lg)
{
  // broadcast u of sample st*16+lm into every lane
  float ust[4];
#pragma unroll
  for(int st = 0; st < 4; ++st) ust[st] = __shfl(u, st * 16 + lm, 64);

  // bpermute source-lane addresses for the mid1->mid2 layout transition
  const int addrA = 4 * (lm + 32 * (lg & 1));
  const int addrB = addrA + 64;
  const bool hisel = (lg & 2) != 0;       // lg>>1 selects jt = 2kt or 2kt+1

  const f32x4 zero = {0.f, 0.f, 0.f, 0.f};
  f32x4 acc1[8][4];
#pragma unroll
  for(int jt = 0; jt < 8; ++jt)
#pragma unroll
    for(int st = 0; st < 4; ++st) acc1[jt][st] = zero;

  // ---- stage1 (build B-frags directly) + mid1: acc1 = W2 * H1^T ----
#pragma unroll
  for(int kt = 0; kt < 4; ++kt){
    const int ko = kt * 32 + lg * 8;      // k = ko + e, e=0..7
    const float4 w1a = *(const float4*)(W1 + ko);
    const float4 w1b = *(const float4*)(W1 + ko + 4);
    const float4 g1a = *(const float4*)(b1 + ko);
    const float4 g1b = *(const float4*)(b1 + ko + 4);
    bf16x8 bv[4];
#pragma unroll
    for(int st = 0; st < 4; ++st){
      const float uv = ust[st];
      float h0 = fmaxf(fmaf(uv, w1a.x, g1a.x), 0.f);
      float h1 = fmaxf(fmaf(uv, w1a.y, g1a.y), 0.f);
      float h2 = fmaxf(fmaf(uv, w1a.z, g1a.z), 0.f);
      float h3 = fmaxf(fmaf(uv, w1a.w, g1a.w), 0.f);
      float h4 = fmaxf(fmaf(uv, w1b.x, g1b.x), 0.f);
      float h5 = fmaxf(fmaf(uv, w1b.y, g1b.y), 0.f);
      float h6 = fmaxf(fmaf(uv, w1b.z, g1b.z), 0.f);
      float h7 = fmaxf(fmaf(uv, w1b.w, g1b.w), 0.f);
      uint4 pk;
      pk.x = pk2(h0, h1); pk.y = pk2(h2, h3);
      pk.z = pk2(h4, h5); pk.w = pk2(h6, h7);
      bv[st] = __builtin_bit_cast(bf16x8, pk);
    }
    const u32 kdw = (u32)(kt * 16 + lg * 4);
#pragma unroll
    for(int jt = 0; jt < 8; ++jt){
      const int j = lm + 16 * jt;
      bf16x8 av = __builtin_bit_cast(bf16x8,
          *(const uint4*)(W2lds + j * 64 + (kdw ^ (u32)((j & 7) << 2))));
#pragma unroll
      for(int st = 0; st < 4; ++st)
        acc1[jt][st] = __builtin_amdgcn_mfma_f32_16x16x32_bf16(av, bv[st], acc1[jt][st], 0, 0, 0);
    }
  }

  // ---- transition: bias+relu+pack; tr[jt][st][d] holds (j=jt*16+lg*4+2d, +1) ----
  u32 tr[8][4][2];
#pragma unroll
  for(int jt = 0; jt < 8; ++jt){
    const float4 bb = *(const float4*)(b2 + jt * 16 + lg * 4);
#pragma unroll
    for(int st = 0; st < 4; ++st){
      float h0 = fmaxf(acc1[jt][st][0] + bb.x, 0.f);
      float h1 = fmaxf(acc1[jt][st][1] + bb.y, 0.f);
      float h2 = fmaxf(acc1[jt][st][2] + bb.z, 0.f);
      float h3 = fmaxf(acc1[jt][st][3] + bb.w, 0.f);
      tr[jt][st][0] = pk2(h0, h1);
      tr[jt][st][1] = pk2(h2, h3);
    }
  }

  // ---- mid2: acc2 = W3 * H2^T, B-frags gathered via ds_bpermute ----
  f32x4 acc2[8][4];
#pragma unroll
  for(int jt = 0; jt < 8; ++jt)
#pragma unroll
    for(int st = 0; st < 4; ++st) acc2[jt][st] = zero;

#pragma unroll
  for(int kt = 0; kt < 4; ++kt){
    bf16x8 bv[4];
#pragma unroll
    for(int st = 0; st < 4; ++st){
      u32 a0 = (u32)__builtin_amdgcn_ds_bpermute(addrA, (int)tr[2*kt  ][st][0]);
      u32 a1 = (u32)__builtin_amdgcn_ds_bpermute(addrA, (int)tr[2*kt+1][st][0]);
      u32 b0 = (u32)__builtin_amdgcn_ds_bpermute(addrA, (int)tr[2*kt  ][st][1]);
      u32 b1_ = (u32)__builtin_amdgcn_ds_bpermute(addrA, (int)tr[2*kt+1][st][1]);
      u32 c0 = (u32)__builtin_amdgcn_ds_bpermute(addrB, (int)tr[2*kt  ][st][0]);
      u32 c1 = (u32)__builtin_amdgcn_ds_bpermute(addrB, (int)tr[2*kt+1][st][0]);
      u32 d0 = (u32)__builtin_amdgcn_ds_bpermute(addrB, (int)tr[2*kt  ][st][1]);
      u32 d1 = (u32)__builtin_amdgcn_ds_bpermute(addrB, (int)tr[2*kt+1][st][1]);
      uint4 pk;
      pk.x = hisel ? a1 : a0;
      pk.y = hisel ? b1_ : b0;
      pk.z = hisel ? c1 : c0;
      pk.w = hisel ? d1 : d0;
      bv[st] = __builtin_bit_cast(bf16x8, pk);
    }
    const u32 kdw = (u32)(kt * 16 + lg * 4);
#pragma unroll
    for(int jt = 0; jt < 8; ++jt){
      const int j = lm + 16 * jt;
      bf16x8 av = __builtin_bit_cast(bf16x8,
          *(const uint4*)(W3lds + j * 64 + (kdw ^ (u32)((j & 7) << 2))));
#pragma unroll
      for(int st = 0; st < 4; ++st)
        acc2[jt][st] = __builtin_amdgcn_mfma_f32_16x16x32_bf16(av, bv[st], acc2[jt][st], 0, 0, 0);
    }
  }

  // ---- out: dot(relu(acc2+b3), W4) with lg-butterfly reduction ----
  float p0 = 0.f, p1 = 0.f, p2 = 0.f, p3 = 0.f;
#pragma unroll
  for(int jt = 0; jt < 8; ++jt){
    const float4 bc = *(const float4*)(b3 + jt * 16 + lg * 4);
    const float4 wc = *(const float4*)(W4 + jt * 16 + lg * 4);
#pragma unroll
    for(int st = 0; st < 4; ++st){
      float q = (st == 0) ? p0 : (st == 1) ? p1 : (st == 2) ? p2 : p3;
      q = fmaf(fmaxf(acc2[jt][st][0] + bc.x, 0.f), wc.x, q);
      q = fmaf(fmaxf(acc2[jt][st][1] + bc.y, 0.f), wc.y, q);
      q = fmaf(fmaxf(acc2[jt][st][2] + bc.z, 0.f), wc.z, q);
      q = fmaf(fmaxf(acc2[jt][st][3] + bc.w, 0.f), wc.w, q);
      if(st == 0) p0 = q; else if(st == 1) p1 = q; else if(st == 2) p2 = q; else p3 = q;
    }
  }
  p0 += __shfl_xor(p0, 16, 64); p0 += __shfl_xor(p0, 32, 64);
  p1 += __shfl_xor(p1, 16, 64); p1 += __shfl_xor(p1, 32, 64);
  p2 += __shfl_xor(p2, 16, 64); p2 += __shfl_xor(p2, 32, 64);
  p3 += __shfl_xor(p3, 16, 64); p3 += __shfl_xor(p3, 32, 64);
  // own sample = lane = lg*16+lm  ->  st index == lg
  return (lg == 0) ? p0 : (lg == 1) ? p1 : (lg == 2) ? p2 : p3;
}

extern "C" __global__ void __launch_bounds__(256, 2)
flow_kernel(const float* __restrict__ x, const float* __restrict__ s_scale,
            const float* __restrict__ sW1, const float* __restrict__ sb1,
            const float* __restrict__ sW2, const float* __restrict__ sb2,
            const float* __restrict__ sW3, const float* __restrict__ sb3,
            const float* __restrict__ sW4, const float* __restrict__ sb4,
            const float* __restrict__ tW1, const float* __restrict__ tb1,
            const float* __restrict__ tW2, const float* __restrict__ tb2,
            const float* __restrict__ tW3, const float* __restrict__ tb3,
            const float* __restrict__ tW4, const float* __restrict__ tb4,
            float* __restrict__ out)
{
  __shared__ u32 Wlds[2][8192];   // 64 KB: W2 / W3 bf16, swizzled

  const int tid = threadIdx.x;
  const int lane = tid & 63, lg = lane >> 4, lm = lane & 15;
  const int gs = (int)blockIdx.x * 256 + tid;   // this thread's sample

  float2 ab = ((const float2*)x)[gs];
  float* scat = out + 2 * BATCH;

#pragma unroll 1
  for(int i = 0; i < LNUM; ++i){
    const int parity = i & 1;
    const float sc = s_scale[i];
    const int off = i * WD, offW = i * (WD * WD);

    // ---------- phase A: s-MLP ----------
    __syncthreads();                       // previous phase done reading Wlds
    stage_W(sW2 + offW, Wlds[0], tid);
    stage_W(sW3 + offW, Wlds[1], tid);
    __syncthreads();
    const float u = parity ? ab.y : ab.x;
    float preS = mlp_frag(u, Wlds[0], Wlds[1], sW1 + off, sb1 + off,
                          sb2 + off, sb3 + off, sW4 + off, lm, lg) + sb4[i];
    const float sv = sc * tanhf(preS);
    scat[i * BATCH + gs] = sv;

    // ---------- phase B: t-MLP + coupling ----------
    __syncthreads();
    stage_W(tW2 + offW, Wlds[0], tid);
    stage_W(tW3 + offW, Wlds[1], tid);
    __syncthreads();
    float preT = mlp_frag(u, Wlds[0], Wlds[1], tW1 + off, tb1 + off,
                          tb2 + off, tb3 + off, tW4 + off, lm, lg) + tb4[i];
    const float tv = tanhf(preT);
    const float e = expf(sv);
    if(parity) ab.x = e * ab.x + tv; else ab.y = e * ab.y + tv;
  }

  ((float2*)out)[gs] = ab;
}

extern "C" void kernel_launch(void* const* d_in, const int* in_sizes, int n_in,
                              void* d_out, int out_size, void* d_ws, size_t ws_size,
                              hipStream_t stream) {
  (void)in_sizes; (void)n_in; (void)d_ws; (void)ws_size; (void)out_size;
  const float* p[18];
  for(int k = 0; k < 18; ++k) p[k] = (const float*)d_in[k];
  dim3 grid(BATCH / 256), block(256);
  hipLaunchKernelGGL(flow_kernel, grid, block, 0, stream,
                     p[0], p[1], p[2], p[3], p[4], p[5], p[6], p[7], p[8], p[9],
                     p[10], p[11], p[12], p[13], p[14], p[15], p[16], p[17],
                     (float*)d_out);
}